// Round 13
// baseline (35.353 us; speedup 1.0000x reference)
//
#include <hip/hip_runtime.h>
#include <math.h>

#define B 64
#define NI 1024
#define NO 1024
#define NC 10
#define ISP0 16          // layer-0 k-split
#define ISP1 16          // layer-1 k-split
#define OBLK 64          // o per block
#define NOB 16           // NO / OBLK

typedef float f4 __attribute__((ext_vector_type(4)));
typedef float f2 __attribute__((ext_vector_type(2)));
typedef _Float16 h8 __attribute__((ext_vector_type(8)));
typedef _Float16 h2 __attribute__((ext_vector_type(2)));

// log(tanh(100*ax)) for ax>=0 via hw exp/log: tanh(z) = 1 - 2/(e^{2z}+1).
// ax==0 -> -inf -> clamp -60000 (f16-representable sentinel; >=2 sentinels
// overflow the f16 partial store to -inf; exp(-inf)=0 == masked product w/ 0).
// Large ax: e=inf -> th=1 -> log = 0 exactly.
__device__ __forceinline__ float lt_fast(float ax) {
    float e  = __expf(200.0f * ax);
    float th = 1.0f - 2.0f / (e + 1.0f);
    return fmaxf(__logf(th), -60000.0f);
}

// ---------------- Layer 0: grid 256 = 16 ob x 16 is; single 64-k tile -------
// R8-proven staging/MFMA + b-major store via a DEDICATED transpose buffer
// (no LDS reuse, no pointer casts). phs0[sp][b][o] (h,s) h2.
__global__ __launch_bounds__(256) void partial0_k(
    const float* __restrict__ x, const float* __restrict__ fc,
    const float* __restrict__ v, h2* __restrict__ phs0, float* __restrict__ y)
{
    const int blk = blockIdx.x, t = threadIdx.x;
    const int ob = blk & (NOB - 1), is = blk >> 4;
    const int o0 = ob * OBLK, i0 = is * 64;

    if (blk == 0 && t < (B * NC) / 4) {        // zero y (head atomically adds)
        f4 z; z.x = 0.f; z.y = 0.f; z.z = 0.f; z.w = 0.f;
        ((f4*)y)[t] = z;
    }

    __shared__ h8 sWf[OBLK][8];   // fc*m   8 KB
    __shared__ h8 sWm[OBLK][8];   // m      8 KB
    __shared__ h8 sX [B][8];      // x      8 KB
    __shared__ h8 sL [B][8];      // lt     8 KB
    __shared__ h2 tr [B][68];     // transpose buffer (dedicated) 17 KB

    const int o = t >> 2, q = t & 3;
    // ---- stage masked weights (R8-proven text) ----
    {
        const float* fp = &fc[(o0 + o) * NI + i0 + q * 16];
        const float* vp = &v [(o0 + o) * NI + i0 + q * 16];
        #pragma unroll
        for (int gg = 0; gg < 2; ++gg) {
            f4 fa = *(const f4*)(fp + gg * 8), fb = *(const f4*)(fp + gg * 8 + 4);
            f4 va = *(const f4*)(vp + gg * 8), vb = *(const f4*)(vp + gg * 8 + 4);
            h8 wf, wm;
            #pragma unroll
            for (int j = 0; j < 4; ++j) {
                bool ma = va[j] > 0.0f, mb = vb[j] > 0.0f;
                wf[j]     = ma ? (_Float16)fa[j] : (_Float16)0.0f;
                wm[j]     = ma ? (_Float16)1.0f  : (_Float16)0.0f;
                wf[4 + j] = mb ? (_Float16)fb[j] : (_Float16)0.0f;
                wm[4 + j] = mb ? (_Float16)1.0f  : (_Float16)0.0f;
            }
            const int g = (q * 2 + gg) ^ (o & 7);
            sWf[o][g] = wf;
            sWm[o][g] = wm;
        }
    }
    // ---- stage activations from raw x (R8-proven text) ----
    {
        const int b = o;
        const float* xr = &x[b * NI + i0 + q * 16];
        #pragma unroll
        for (int gg = 0; gg < 2; ++gg) {
            f4 xa = *(const f4*)(xr + gg * 8), xb = *(const f4*)(xr + gg * 8 + 4);
            h8 xv, lv;
            #pragma unroll
            for (int j = 0; j < 4; ++j) {
                xv[j]     = (_Float16)xa[j];
                lv[j]     = (_Float16)lt_fast(fabsf(xa[j]));
                xv[4 + j] = (_Float16)xb[j];
                lv[4 + j] = (_Float16)lt_fast(fabsf(xb[j]));
            }
            const int g = (q * 2 + gg) ^ (b & 7);
            sX[b][g] = xv;
            sL[b][g] = lv;
        }
    }
    __syncthreads();

    // ---- MFMA (R8-proven text) ----
    const int w = t >> 6, l = t & 63;
    const int r16 = l & 15, ks = l >> 4;
    const int sw0 = ks ^ (r16 & 7), sw1 = (ks + 4) ^ (r16 & 7);
    h8 aF0 = sWf[w * 16 + r16][sw0], aF1 = sWf[w * 16 + r16][sw1];
    h8 aM0 = sWm[w * 16 + r16][sw0], aM1 = sWm[w * 16 + r16][sw1];
    f4 accH[4] = {}, accS[4] = {};
    #pragma unroll
    for (int bq = 0; bq < 4; ++bq) {
        h8 bX0 = sX[bq * 16 + r16][sw0], bX1 = sX[bq * 16 + r16][sw1];
        h8 bL0 = sL[bq * 16 + r16][sw0], bL1 = sL[bq * 16 + r16][sw1];
        accH[bq] = __builtin_amdgcn_mfma_f32_16x16x32_f16(aF0, bX0, accH[bq], 0, 0, 0);
        accH[bq] = __builtin_amdgcn_mfma_f32_16x16x32_f16(aF1, bX1, accH[bq], 0, 0, 0);
        accS[bq] = __builtin_amdgcn_mfma_f32_16x16x32_f16(aM0, bL0, accS[bq], 0, 0, 0);
        accS[bq] = __builtin_amdgcn_mfma_f32_16x16x32_f16(aM1, bL1, accS[bq], 0, 0, 0);
    }

    // ---- transpose to b-major via dedicated tr (no reuse hazard) ----
    // D layout (m89): row(o_local) = ks*4 + r (+ w*16), col(b) = bq*16 + r16
    #pragma unroll
    for (int bq = 0; bq < 4; ++bq)
        #pragma unroll
        for (int r = 0; r < 4; ++r) {
            h2 pv;
            pv.x = (_Float16)accH[bq][r];
            pv.y = (_Float16)accS[bq][r];
            tr[bq * 16 + r16][w * 16 + ks * 4 + r] = pv;
        }
    __syncthreads();
    const int br = t >> 2, qc = t & 3;
    const f4* srcp = (const f4*)&tr[br][qc * 16];
    f4 d0 = srcp[0], d1 = srcp[1], d2 = srcp[2], d3 = srcp[3];
    f4* dst = (f4*)&phs0[(size_t)(is * B + br) * NO + o0 + qc * 16];
    dst[0] = d0; dst[1] = d1; dst[2] = d2; dst[3] = d3;
}

// ---------------- Layer 1: grid 256 = 16 ob x 16 is (R10-proven text) -------
// Finalizes its own 64-k slice of layer-0 inline from phs0 (L2-hot), then the
// R8-proven 64o x 64k MFMA tile; phs1 stored o-major [sp][o][b].
__global__ __launch_bounds__(256, 2) void partial1_k(
    const h2* __restrict__ phs0, const float* __restrict__ fc,
    const float* __restrict__ v, h2* __restrict__ phs1)
{
    const int blk = blockIdx.x, t = threadIdx.x;
    const int ob = blk & (NOB - 1), is = blk >> 4;
    const int o0 = ob * OBLK, i0 = is * 64;

    __shared__ h8 sWf[OBLK][8];
    __shared__ h8 sWm[OBLK][8];
    __shared__ h8 sX [B][8];
    __shared__ h8 sL [B][8];

    const int o = t >> 2, q = t & 3;
    // ---- weights ----
    {
        const float* fp = &fc[(o0 + o) * NI + i0 + q * 16];
        const float* vp = &v [(o0 + o) * NI + i0 + q * 16];
        #pragma unroll
        for (int gg = 0; gg < 2; ++gg) {
            f4 fa = *(const f4*)(fp + gg * 8), fb = *(const f4*)(fp + gg * 8 + 4);
            f4 va = *(const f4*)(vp + gg * 8), vb = *(const f4*)(vp + gg * 8 + 4);
            h8 wf, wm;
            #pragma unroll
            for (int j = 0; j < 4; ++j) {
                bool ma = va[j] > 0.0f, mb = vb[j] > 0.0f;
                wf[j]     = ma ? (_Float16)fa[j] : (_Float16)0.0f;
                wm[j]     = ma ? (_Float16)1.0f  : (_Float16)0.0f;
                wf[4 + j] = mb ? (_Float16)fb[j] : (_Float16)0.0f;
                wm[4 + j] = mb ? (_Float16)1.0f  : (_Float16)0.0f;
            }
            const int g = (q * 2 + gg) ^ (o & 7);
            sWf[o][g] = wf;
            sWm[o][g] = wm;
        }
    }
    // ---- activations: finalize h0 for k = i0+q*16 .. +16 of b = o ----
    {
        const int b = o, kb = i0 + q * 16;
        float sh[16] = {}, ss[16] = {};
        #pragma unroll
        for (int sp = 0; sp < ISP0; ++sp) {
            const f4* pp = (const f4*)&phs0[(size_t)(sp * B + b) * NO + kb];
            #pragma unroll
            for (int u = 0; u < 4; ++u) {
                f4 pk = pp[u];
                #pragma unroll
                for (int j = 0; j < 4; ++j) {
                    h2 pv = __builtin_bit_cast(h2, pk[j]);
                    sh[u * 4 + j] += (float)pv.x;
                    ss[u * 4 + j] += (float)pv.y;
                }
            }
        }
        #pragma unroll
        for (int gg = 0; gg < 2; ++gg) {
            h8 xv, lv;
            #pragma unroll
            for (int j = 0; j < 8; ++j) {
                float h = fmaxf(sh[gg * 8 + j] * __expf(ss[gg * 8 + j]), 0.0f);
                xv[j] = (_Float16)h;
                lv[j] = (_Float16)lt_fast(h);
            }
            const int g = (q * 2 + gg) ^ (b & 7);
            sX[b][g] = xv;
            sL[b][g] = lv;
        }
    }
    __syncthreads();

    const int w = t >> 6, l = t & 63;
    const int r16 = l & 15, ks = l >> 4;
    const int sw0 = ks ^ (r16 & 7), sw1 = (ks + 4) ^ (r16 & 7);
    h8 aF0 = sWf[w * 16 + r16][sw0], aF1 = sWf[w * 16 + r16][sw1];
    h8 aM0 = sWm[w * 16 + r16][sw0], aM1 = sWm[w * 16 + r16][sw1];
    f4 accH[4] = {}, accS[4] = {};
    #pragma unroll
    for (int bq = 0; bq < 4; ++bq) {
        h8 bX0 = sX[bq * 16 + r16][sw0], bX1 = sX[bq * 16 + r16][sw1];
        h8 bL0 = sL[bq * 16 + r16][sw0], bL1 = sL[bq * 16 + r16][sw1];
        accH[bq] = __builtin_amdgcn_mfma_f32_16x16x32_f16(aF0, bX0, accH[bq], 0, 0, 0);
        accH[bq] = __builtin_amdgcn_mfma_f32_16x16x32_f16(aF1, bX1, accH[bq], 0, 0, 0);
        accS[bq] = __builtin_amdgcn_mfma_f32_16x16x32_f16(aM0, bL0, accS[bq], 0, 0, 0);
        accS[bq] = __builtin_amdgcn_mfma_f32_16x16x32_f16(aM1, bL1, accS[bq], 0, 0, 0);
    }
    const size_t obase = (size_t)(is * NO + o0 + w * 16 + ks * 4) * B;
    #pragma unroll
    for (int bq = 0; bq < 4; ++bq)
        #pragma unroll
        for (int r = 0; r < 4; ++r) {
            h2 pv;
            pv.x = (_Float16)accH[bq][r];
            pv.y = (_Float16)accS[bq][r];
            phs1[obase + r * B + bq * 16 + r16] = pv;
        }
}

// ---------------- Finals (grid 256, R10-proven): phs -> xh0, xh1 ------------
__global__ __launch_bounds__(256) void final_k(
    const h2* __restrict__ phs0, const h2* __restrict__ phs1,
    _Float16* __restrict__ xh0, _Float16* __restrict__ xh1)
{
    const int g = blockIdx.x * 256 + threadIdx.x;
    // xh1[o][b] from phs1 (o-major): consecutive t -> consecutive b, coalesced
    {
        const int o = g >> 6, b = g & 63;
        float sh = 0.f, ss = 0.f;
        #pragma unroll
        for (int sp = 0; sp < ISP1; ++sp) {
            h2 p = phs1[(size_t)(sp * NO + o) * B + b];
            sh += (float)p.x; ss += (float)p.y;
        }
        xh1[(size_t)o * B + b] = (_Float16)fmaxf(sh * __expf(ss), 0.0f);
    }
    // xh0[b][o] from phs0 (b-major): consecutive t -> consecutive o, coalesced
    {
        const int b = g >> 10, o = g & 1023;
        float sh = 0.f, ss = 0.f;
        #pragma unroll
        for (int sp = 0; sp < ISP0; ++sp) {
            h2 p = phs0[(size_t)(sp * B + b) * NO + o];
            sh += (float)p.x; ss += (float)p.y;
        }
        xh0[(size_t)b * NO + o] = (_Float16)fmaxf(sh * __expf(ss), 0.0f);
    }
}

// ---------------- Head (grid 16, R10-proven): L2-hot xh + 16-way atomics ----
__global__ __launch_bounds__(256) void head_k(
    const _Float16* __restrict__ xh0, const _Float16* __restrict__ xh1,
    const float* __restrict__ hd0, const float* __restrict__ hd1,
    float* __restrict__ y)
{
    const int blk = blockIdx.x, t = threadIdx.x;
    const int o0 = blk * 64;
    __shared__ float hh0[64][65];   // stride 65 (odd): column access bank-free
    __shared__ float hh1[64][65];
    __shared__ f2 hdl[NC][64];

    #pragma unroll
    for (int rep = 0; rep < 16; ++rep) {
        const int cell = t + rep * 256;
        {   // h1: xh1 o-major [o][B]; consecutive t -> consecutive b
            const int ol = cell >> 6, b = cell & 63;
            hh1[ol][b] = (float)xh1[(size_t)(o0 + ol) * B + b];
        }
        {   // h0: xh0 b-major [b][NO]; consecutive t -> consecutive ol
            const int ol = cell & 63, b = cell >> 6;
            hh0[ol][b] = (float)xh0[(size_t)b * NO + o0 + ol];
        }
    }
    for (int e = t; e < NC * 64; e += 256) {
        const int c = e >> 6, ol = e & 63;
        f2 d; d.x = hd0[c * NO + o0 + ol]; d.y = hd1[c * NO + o0 + ol];
        hdl[c][ol] = d;
    }
    __syncthreads();

    const int w = t >> 6, lane = t & 63;
    for (int cc = w; cc < NC; cc += 4) {
        float acc = 0.f;
        #pragma unroll 8
        for (int ol = 0; ol < 64; ++ol) {
            f2 dv = hdl[cc][ol];                    // wave-uniform broadcast
            acc = fmaf(hh0[ol][lane], dv.x, fmaf(hh1[ol][lane], dv.y, acc));
        }
        atomicAdd(&y[lane * NC + cc], acc);         // 16 contenders (R6/R8-proven)
    }
}

extern "C" void kernel_launch(void* const* d_in, const int* in_sizes, int n_in,
                              void* d_out, int out_size, void* d_ws, size_t ws_size,
                              hipStream_t stream) {
    const float* x   = (const float*)d_in[0];
    const float* v0  = (const float*)d_in[1];
    const float* fc0 = (const float*)d_in[2];
    const float* hd0 = (const float*)d_in[3];
    const float* v1  = (const float*)d_in[4];
    const float* fc1 = (const float*)d_in[5];
    const float* hd1 = (const float*)d_in[6];
    float* y = (float*)d_out;

    h2* phs0      = (h2*)d_ws;                                   // 4 MB [sp][b][o]
    h2* phs1      = phs0 + (size_t)ISP0 * B * NO;                // 4 MB [sp][o][b]
    _Float16* xh0 = (_Float16*)(phs1 + (size_t)ISP1 * NO * B);   // 128 KB [b][o]
    _Float16* xh1 = xh0 + (size_t)B * NO;                        // 128 KB [o][B]

    partial0_k<<<256, 256, 0, stream>>>(x, fc0, v0, phs0, y);
    partial1_k<<<256, 256, 0, stream>>>(phs0, fc1, v1, phs1);
    final_k   <<<256, 256, 0, stream>>>(phs0, phs1, xh0, xh1);
    head_k    <<<16, 256, 0, stream>>>(xh0, xh1, hd0, hd1, y);
}

// Round 14
// 26.140 us; speedup vs baseline: 1.3524x; 1.3524x over previous
//
#include <hip/hip_runtime.h>
#include <math.h>

#define B 64
#define NI 1024
#define NO 1024
#define NC 10
// layer 0 (R8-proven geometry)
#define ISP0 16
#define OBLK 64
#define NOB 16
// layer 1 (new geometry: small o-tile, long k)
#define ISP1 4
#define OB1 16
#define NOB1 64

typedef float f4 __attribute__((ext_vector_type(4)));
typedef float f2 __attribute__((ext_vector_type(2)));
typedef _Float16 h8 __attribute__((ext_vector_type(8)));
typedef _Float16 h2 __attribute__((ext_vector_type(2)));

// log(tanh(100*ax)) for ax>=0 via hw exp/log: tanh(z) = 1 - 2/(e^{2z}+1).
// ax==0 -> -inf -> clamp -60000 (f16-representable sentinel; >=2 sentinels
// overflow the f16 partial store to -inf; exp(-inf)=0 == masked product w/ 0).
// Large ax: e=inf -> th=1 -> log = 0 exactly.
__device__ __forceinline__ float lt_fast(float ax) {
    float e  = __expf(200.0f * ax);
    float th = 1.0f - 2.0f / (e + 1.0f);
    return fmaxf(__logf(th), -60000.0f);
}

// ---------------- Layer 0 (R8 text): grid 256 = 16 ob x 16 is ---------------
// phs0[sp][o][b] (h,s) h2, o-major.
__global__ __launch_bounds__(256, 2) void partial0_k(
    const float* __restrict__ xraw, const float* __restrict__ fc,
    const float* __restrict__ v, h2* __restrict__ phs0)
{
    const int blk = blockIdx.x, t = threadIdx.x;
    const int ob = blk & (NOB - 1), is = blk >> 4;
    const int o0 = ob * OBLK, i0 = is * 64;

    __shared__ h8 sWf[OBLK][8];   // fc*m   8 KB
    __shared__ h8 sWm[OBLK][8];   // m      8 KB
    __shared__ h8 sX [B][8];      // x      8 KB
    __shared__ h8 sL [B][8];      // lt     8 KB

    // ---- stage masked weights: thread = (o = t>>2, q = t&3) ----
    {
        const int o = t >> 2, q = t & 3;
        const float* fp = &fc[(o0 + o) * NI + i0 + q * 16];
        const float* vp = &v [(o0 + o) * NI + i0 + q * 16];
        #pragma unroll
        for (int gg = 0; gg < 2; ++gg) {
            f4 fa = *(const f4*)(fp + gg * 8), fb = *(const f4*)(fp + gg * 8 + 4);
            f4 va = *(const f4*)(vp + gg * 8), vb = *(const f4*)(vp + gg * 8 + 4);
            h8 wf, wm;
            #pragma unroll
            for (int j = 0; j < 4; ++j) {
                bool ma = va[j] > 0.0f, mb = vb[j] > 0.0f;
                wf[j]     = ma ? (_Float16)fa[j] : (_Float16)0.0f;
                wm[j]     = ma ? (_Float16)1.0f  : (_Float16)0.0f;
                wf[4 + j] = mb ? (_Float16)fb[j] : (_Float16)0.0f;
                wm[4 + j] = mb ? (_Float16)1.0f  : (_Float16)0.0f;
            }
            const int g = (q * 2 + gg) ^ (o & 7);
            sWf[o][g] = wf;
            sWm[o][g] = wm;
        }
    }
    // ---- stage activations from raw x (lt inline) ----
    {
        const int b = t >> 2, q = t & 3;
        const float* xr = &xraw[b * NI + i0 + q * 16];
        #pragma unroll
        for (int gg = 0; gg < 2; ++gg) {
            f4 xa = *(const f4*)(xr + gg * 8), xb = *(const f4*)(xr + gg * 8 + 4);
            h8 xv, lv;
            #pragma unroll
            for (int j = 0; j < 4; ++j) {
                xv[j]     = (_Float16)xa[j];
                lv[j]     = (_Float16)lt_fast(fabsf(xa[j]));
                xv[4 + j] = (_Float16)xb[j];
                lv[4 + j] = (_Float16)lt_fast(fabsf(xb[j]));
            }
            const int g = (q * 2 + gg) ^ (b & 7);
            sX[b][g] = xv;
            sL[b][g] = lv;
        }
    }
    __syncthreads();

    // ---- MFMA: wave w -> o rows [16w,16w+16); 4 b-quadrants x 2 k-halves ----
    const int w = t >> 6, l = t & 63;
    const int r16 = l & 15, ks = l >> 4;
    const int sw0 = ks ^ (r16 & 7), sw1 = (ks + 4) ^ (r16 & 7);
    h8 aF0 = sWf[w * 16 + r16][sw0], aF1 = sWf[w * 16 + r16][sw1];
    h8 aM0 = sWm[w * 16 + r16][sw0], aM1 = sWm[w * 16 + r16][sw1];
    f4 accH[4] = {}, accS[4] = {};
    #pragma unroll
    for (int bq = 0; bq < 4; ++bq) {
        h8 bX0 = sX[bq * 16 + r16][sw0], bX1 = sX[bq * 16 + r16][sw1];
        h8 bL0 = sL[bq * 16 + r16][sw0], bL1 = sL[bq * 16 + r16][sw1];
        accH[bq] = __builtin_amdgcn_mfma_f32_16x16x32_f16(aF0, bX0, accH[bq], 0, 0, 0);
        accH[bq] = __builtin_amdgcn_mfma_f32_16x16x32_f16(aF1, bX1, accH[bq], 0, 0, 0);
        accS[bq] = __builtin_amdgcn_mfma_f32_16x16x32_f16(aM0, bL0, accS[bq], 0, 0, 0);
        accS[bq] = __builtin_amdgcn_mfma_f32_16x16x32_f16(aM1, bL1, accS[bq], 0, 0, 0);
    }
    // ---- store: D row = ks*4 + r (o), col = r16 (b) [m89 layout] ----
    const size_t obase = (size_t)(is * NO + o0 + w * 16 + ks * 4) * B;
    #pragma unroll
    for (int bq = 0; bq < 4; ++bq)
        #pragma unroll
        for (int r = 0; r < 4; ++r) {
            h2 pv;
            pv.x = (_Float16)accH[bq][r];
            pv.y = (_Float16)accS[bq][r];
            phs0[obase + r * B + bq * 16 + r16] = pv;
        }
}

// ---------------- Final-0 (R8 text, grid 256): phs0 -> xp, xh0; zero y ------
__global__ __launch_bounds__(256) void final0_k(
    const h2* __restrict__ phs0, h2* __restrict__ xp, _Float16* __restrict__ xh0,
    float* __restrict__ y)
{
    const int g = blockIdx.x * 256 + threadIdx.x;
    if (g < B * NC) y[g] = 0.0f;
    const int o = g >> 6, b = g & 63;
    float sh = 0.f, ss = 0.f;
    #pragma unroll
    for (int sp = 0; sp < ISP0; ++sp) {
        h2 p = phs0[(size_t)(sp * NO + o) * B + b];   // coalesced
        sh += (float)p.x;
        ss += (float)p.y;
    }
    float h = fmaxf(sh * __expf(ss), 0.0f);
    h2 pr; pr.x = (_Float16)h; pr.y = (_Float16)lt_fast(h);
    xp[(size_t)b * NI + o] = pr;            // scattered 4B, L2-absorbed (256 KB)
    xh0[(size_t)o * B + b] = (_Float16)h;   // coalesced, o-major [o][B]
}

// ---------------- Layer 1 (new): grid 256 = 64 ob x 4 is --------------------
// Block: 16 o x 256 k x 64 b, single staging phase (80 KB LDS), 16 MFMA/wave;
// wave w owns output quadrant (o 0..15) x (b = w*16..w*16+15).
// phs1[sp][o][b] o-major, 1 MB total.
__global__ __launch_bounds__(256) void partial1_k(
    const h2* __restrict__ xp, const float* __restrict__ fc,
    const float* __restrict__ v, h2* __restrict__ phs1)
{
    const int blk = blockIdx.x, t = threadIdx.x;
    const int ob = blk & (NOB1 - 1), is = blk >> 6;
    const int o0 = ob * OB1, i0 = is * 256;

    __shared__ h8 sWf[OB1][32];   // 8 KB
    __shared__ h8 sWm[OB1][32];   // 8 KB
    __shared__ h8 sX [B][32];     // 32 KB
    __shared__ h8 sL [B][32];     // 32 KB

    // ---- weights: thread = (o = t>>4, q = t&15) -> granules q*2, q*2+1 ----
    {
        const int o = t >> 4, q = t & 15;
        const float* fp = &fc[(o0 + o) * NI + i0 + q * 16];
        const float* vp = &v [(o0 + o) * NI + i0 + q * 16];
        #pragma unroll
        for (int gg = 0; gg < 2; ++gg) {
            f4 fa = *(const f4*)(fp + gg * 8), fb = *(const f4*)(fp + gg * 8 + 4);
            f4 va = *(const f4*)(vp + gg * 8), vb = *(const f4*)(vp + gg * 8 + 4);
            h8 wf, wm;
            #pragma unroll
            for (int j = 0; j < 4; ++j) {
                bool ma = va[j] > 0.0f, mb = vb[j] > 0.0f;
                wf[j]     = ma ? (_Float16)fa[j] : (_Float16)0.0f;
                wm[j]     = ma ? (_Float16)1.0f  : (_Float16)0.0f;
                wf[4 + j] = mb ? (_Float16)fb[j] : (_Float16)0.0f;
                wm[4 + j] = mb ? (_Float16)1.0f  : (_Float16)0.0f;
            }
            const int g = (q * 2 + gg) ^ (o & 7);
            sWf[o][g] = wf;
            sWm[o][g] = wm;
        }
    }
    // ---- activations: thread = (b = t>>2, q = t&3) -> granules q*8..q*8+7 ----
    {
        const int b = t >> 2, q = t & 3;
        #pragma unroll
        for (int j = 0; j < 8; ++j) {
            const int g = q * 8 + j;
            const f4* s4 = (const f4*)&xp[(size_t)b * NI + i0 + g * 8];
            f4 q0 = s4[0], q1 = s4[1];
            h8 xv, lv;
            #pragma unroll
            for (int jj = 0; jj < 4; ++jj) {
                h2 p0 = __builtin_bit_cast(h2, q0[jj]);
                h2 p1 = __builtin_bit_cast(h2, q1[jj]);
                xv[jj] = p0.x;     lv[jj] = p0.y;
                xv[4 + jj] = p1.x; lv[4 + jj] = p1.y;
            }
            sX[b][g ^ (b & 7)] = xv;
            sL[b][g ^ (b & 7)] = lv;
        }
    }
    __syncthreads();

    // ---- MFMA: 4 k-tiles of 64; A rows = o (r16), B rows = b (w*16+r16) ----
    const int w = t >> 6, l = t & 63;
    const int r16 = l & 15, ks = l >> 4;
    f4 accH = {}, accS = {};
    #pragma unroll
    for (int kt = 0; kt < 4; ++kt) {
        const int g0 = (kt * 8 + ks) ^ (r16 & 7);
        const int g1 = (kt * 8 + ks + 4) ^ (r16 & 7);
        h8 aF0 = sWf[r16][g0], aF1 = sWf[r16][g1];
        h8 aM0 = sWm[r16][g0], aM1 = sWm[r16][g1];
        h8 bX0 = sX[w * 16 + r16][g0], bX1 = sX[w * 16 + r16][g1];
        h8 bL0 = sL[w * 16 + r16][g0], bL1 = sL[w * 16 + r16][g1];
        accH = __builtin_amdgcn_mfma_f32_16x16x32_f16(aF0, bX0, accH, 0, 0, 0);
        accH = __builtin_amdgcn_mfma_f32_16x16x32_f16(aF1, bX1, accH, 0, 0, 0);
        accS = __builtin_amdgcn_mfma_f32_16x16x32_f16(aM0, bL0, accS, 0, 0, 0);
        accS = __builtin_amdgcn_mfma_f32_16x16x32_f16(aM1, bL1, accS, 0, 0, 0);
    }
    // ---- store: o_local = ks*4 + r, b = w*16 + r16 [m89 layout] ----
    const size_t obase = (size_t)(is * NO + o0 + ks * 4) * B + w * 16 + r16;
    #pragma unroll
    for (int r = 0; r < 4; ++r) {
        h2 pv;
        pv.x = (_Float16)accH[r];
        pv.y = (_Float16)accS[r];
        phs1[obase + (size_t)r * B] = pv;
    }
}

// ---------------- Tail (grid 16): reduce phs1 (1 MB, L2-hot) + head ---------
__global__ __launch_bounds__(256) void tail_k(
    const h2* __restrict__ phs1, const _Float16* __restrict__ xh0,
    const float* __restrict__ hd0, const float* __restrict__ hd1,
    float* __restrict__ y)
{
    const int blk = blockIdx.x, t = threadIdx.x;
    const int o0 = blk * 64;
    __shared__ float hh0[64][65];   // stride 65 (odd): column access bank-free
    __shared__ float hh1[64][65];
    __shared__ f2 hdl[NC][64];

    #pragma unroll
    for (int rep = 0; rep < 16; ++rep) {
        const int cell = t + rep * 256;
        const int ol = cell >> 6, b = cell & 63;   // consecutive t -> consecutive b
        float sh = 0.f, ss = 0.f;
        #pragma unroll
        for (int sp = 0; sp < ISP1; ++sp) {
            h2 p = phs1[(size_t)(sp * NO + o0 + ol) * B + b];   // coalesced
            sh += (float)p.x; ss += (float)p.y;
        }
        hh1[ol][b] = fmaxf(sh * __expf(ss), 0.0f);
        hh0[ol][b] = (float)xh0[(size_t)(o0 + ol) * B + b];     // coalesced
    }
    for (int e = t; e < NC * 64; e += 256) {
        const int c = e >> 6, ol = e & 63;
        f2 d; d.x = hd0[c * NO + o0 + ol]; d.y = hd1[c * NO + o0 + ol];
        hdl[c][ol] = d;
    }
    __syncthreads();

    const int w = t >> 6, lane = t & 63;
    for (int cc = w; cc < NC; cc += 4) {
        float acc = 0.f;
        #pragma unroll 8
        for (int ol = 0; ol < 64; ++ol) {
            f2 dv = hdl[cc][ol];                    // wave-uniform broadcast
            acc = fmaf(hh0[ol][lane], dv.x, fmaf(hh1[ol][lane], dv.y, acc));
        }
        atomicAdd(&y[lane * NC + cc], acc);         // 16 contenders (R6/R8-proven)
    }
}

extern "C" void kernel_launch(void* const* d_in, const int* in_sizes, int n_in,
                              void* d_out, int out_size, void* d_ws, size_t ws_size,
                              hipStream_t stream) {
    const float* x   = (const float*)d_in[0];
    const float* v0  = (const float*)d_in[1];
    const float* fc0 = (const float*)d_in[2];
    const float* hd0 = (const float*)d_in[3];
    const float* v1  = (const float*)d_in[4];
    const float* fc1 = (const float*)d_in[5];
    const float* hd1 = (const float*)d_in[6];
    float* y = (float*)d_out;

    h2* phs0      = (h2*)d_ws;                                   // 4 MB [sp][o][b]
    h2* phs1      = phs0 + (size_t)ISP0 * NO * B;                // 1 MB [sp][o][b]
    h2* xp        = phs1 + (size_t)ISP1 * NO * B;                // 256 KB [b][NI] pairs
    _Float16* xh0 = (_Float16*)(xp + (size_t)B * NI);            // 128 KB [o][B]

    partial0_k<<<NOB * ISP0,  256, 0, stream>>>(x, fc0, v0, phs0);     // 256
    final0_k  <<<256,         256, 0, stream>>>(phs0, xp, xh0, y);
    partial1_k<<<NOB1 * ISP1, 256, 0, stream>>>(xp, fc1, v1, phs1);    // 256
    tail_k    <<<16,          256, 0, stream>>>(phs1, xh0, hd0, hd1, y);
}